// Round 1
// baseline (734.464 us; speedup 1.0000x reference)
//
#include <hip/hip_runtime.h>
#include <hip/hip_bf16.h>
#include <type_traits>

typedef __attribute__((ext_vector_type(8))) short short8;
typedef __attribute__((ext_vector_type(4))) float f32x4;

__device__ inline float bf2f(unsigned short u) {
    union { unsigned int i; float f; } x; x.i = ((unsigned int)u) << 16; return x.f;
}
__device__ inline unsigned short f2bf(float f) {
    union { float f; unsigned int u; } x; x.f = f;
    return (unsigned short)((x.u + 0x7fffu + ((x.u >> 16) & 1u)) >> 16);
}

// row_ptr[n] = lower_bound(edge_dst, n); edge_dst is sorted.
__global__ void rowptr_kernel(const int* __restrict__ dst, int* __restrict__ rp,
                              int nedges, int nnodes) {
    int n = blockIdx.x * blockDim.x + threadIdx.x;
    if (n > nnodes) return;
    int lo = 0, hi = nedges;
    while (lo < hi) {
        int mid = (lo + hi) >> 1;
        if (dst[mid] < n) lo = mid + 1; else hi = mid;
    }
    rp[n] = lo;
}

// Wt[n][k] = bf16(W[k][n]); W is [256][256] row-major (k,n).
__global__ void wconv_kernel(const float* __restrict__ W, unsigned short* __restrict__ Wt) {
    int n = blockIdx.x, k = threadIdx.x;
    Wt[(size_t)n * 256 + k] = f2bf(W[(size_t)k * 256 + n]);
}

// WLt[c][k]: c<64 -> WL1[k][c], else WL2[k][c-64]. WL* are [256][64].
__global__ void wlconv_kernel(const float* __restrict__ WL1, const float* __restrict__ WL2,
                              unsigned short* __restrict__ Wt) {
    int c = blockIdx.x, k = threadIdx.x;
    float v = (c < 64) ? WL1[(size_t)k * 64 + c] : WL2[(size_t)k * 64 + (c - 64)];
    Wt[(size_t)c * 256 + k] = f2bf(v);
}

// C[M][256] (bf16) = A[M][256] @ Bt^T, Bt is [256][256] bf16 pre-transposed [n][k].
// AT = float (x input, converted inline) or unsigned short (bf16 h input).
template <typename AT>
__global__ __launch_bounds__(256) void gemm_kernel(
    const AT* __restrict__ A, const unsigned short* __restrict__ Bt,
    unsigned short* __restrict__ C, int M)
{
    __shared__ __align__(16) unsigned short As[128][40]; // K-pad 32->40: 2-way bank alias only
    __shared__ __align__(16) unsigned short Bs[128][40];
    const int t = threadIdx.x;
    const int row0 = blockIdx.x * 128;
    const int col0 = blockIdx.y * 128;
    const int wid = t >> 6, lane = t & 63;
    const int wm = (wid >> 1) * 64, wn = (wid & 1) * 64;
    const int qk = (lane >> 4) * 8, r16 = lane & 15;

    f32x4 acc[4][4];
#pragma unroll
    for (int i = 0; i < 4; i++)
#pragma unroll
        for (int j = 0; j < 4; j++) acc[i][j] = (f32x4){0.f, 0.f, 0.f, 0.f};

    for (int k0 = 0; k0 < 256; k0 += 32) {
#pragma unroll
        for (int i = 0; i < 2; i++) {
            int ch = t + i * 256;          // 512 chunks of 8 elements
            int m = ch >> 2;               // 0..127
            int ko = (ch & 3) * 8;         // 0,8,16,24
            int row = row0 + m;
            uint4 pk;
            if (row < M) {
                if constexpr (std::is_same<AT, float>::value) {
                    const float4* p = (const float4*)(A + (size_t)row * 256 + k0 + ko);
                    float4 u = p[0], v = p[1];
                    pk.x = (unsigned int)f2bf(u.x) | ((unsigned int)f2bf(u.y) << 16);
                    pk.y = (unsigned int)f2bf(u.z) | ((unsigned int)f2bf(u.w) << 16);
                    pk.z = (unsigned int)f2bf(v.x) | ((unsigned int)f2bf(v.y) << 16);
                    pk.w = (unsigned int)f2bf(v.z) | ((unsigned int)f2bf(v.w) << 16);
                } else {
                    pk = *(const uint4*)(A + (size_t)row * 256 + k0 + ko);
                }
            } else {
                pk = (uint4){0u, 0u, 0u, 0u};
            }
            *(uint4*)(&As[m][ko]) = pk;
            // B tile: Bs[n][kk] = Bt[col0+n][k0+kk]
            *(uint4*)(&Bs[m][ko]) = *(const uint4*)(Bt + (size_t)(col0 + m) * 256 + k0 + ko);
        }
        __syncthreads();
        short8 av[4], bv[4];
#pragma unroll
        for (int mt = 0; mt < 4; mt++) av[mt] = *(const short8*)(&As[wm + mt * 16 + r16][qk]);
#pragma unroll
        for (int nt = 0; nt < 4; nt++) bv[nt] = *(const short8*)(&Bs[wn + nt * 16 + r16][qk]);
#pragma unroll
        for (int mt = 0; mt < 4; mt++)
#pragma unroll
            for (int nt = 0; nt < 4; nt++)
                acc[mt][nt] = __builtin_amdgcn_mfma_f32_16x16x32_bf16(av[mt], bv[nt], acc[mt][nt], 0, 0, 0);
        __syncthreads();
    }
    // C/D layout: col = lane&15, row = (lane>>4)*4 + r  [measured m89/m91]
#pragma unroll
    for (int mt = 0; mt < 4; mt++) {
#pragma unroll
        for (int r = 0; r < 4; r++) {
            int row = row0 + wm + mt * 16 + (lane >> 4) * 4 + r;
            if (row >= M) continue;
#pragma unroll
            for (int nt = 0; nt < 4; nt++) {
                int col = col0 + wn + nt * 16 + r16;
                C[(size_t)row * 256 + col] = f2bf(acc[mt][nt][r]);
            }
        }
    }
}

// logits = h2 @ WLt^T + bias, cols 0..63 -> out[row*64+c], 64..127 -> out[M*64 + row*64 + c-64]
__global__ __launch_bounds__(256) void head_kernel(
    const unsigned short* __restrict__ A, const unsigned short* __restrict__ Bt,
    const float* __restrict__ bL1, const float* __restrict__ bL2,
    float* __restrict__ out, int M)
{
    __shared__ __align__(16) unsigned short As[128][40];
    __shared__ __align__(16) unsigned short Bs[128][40];
    const int t = threadIdx.x;
    const int row0 = blockIdx.x * 128;
    const int wid = t >> 6, lane = t & 63;
    const int wm = (wid >> 1) * 64, wn = (wid & 1) * 64;
    const int qk = (lane >> 4) * 8, r16 = lane & 15;

    f32x4 acc[4][4];
#pragma unroll
    for (int i = 0; i < 4; i++)
#pragma unroll
        for (int j = 0; j < 4; j++) acc[i][j] = (f32x4){0.f, 0.f, 0.f, 0.f};

    for (int k0 = 0; k0 < 256; k0 += 32) {
#pragma unroll
        for (int i = 0; i < 2; i++) {
            int ch = t + i * 256;
            int m = ch >> 2;
            int ko = (ch & 3) * 8;
            int row = row0 + m;
            uint4 pk = (uint4){0u, 0u, 0u, 0u};
            if (row < M) pk = *(const uint4*)(A + (size_t)row * 256 + k0 + ko);
            *(uint4*)(&As[m][ko]) = pk;
            *(uint4*)(&Bs[m][ko]) = *(const uint4*)(Bt + (size_t)m * 256 + k0 + ko);
        }
        __syncthreads();
        short8 av[4], bv[4];
#pragma unroll
        for (int mt = 0; mt < 4; mt++) av[mt] = *(const short8*)(&As[wm + mt * 16 + r16][qk]);
#pragma unroll
        for (int nt = 0; nt < 4; nt++) bv[nt] = *(const short8*)(&Bs[wn + nt * 16 + r16][qk]);
#pragma unroll
        for (int mt = 0; mt < 4; mt++)
#pragma unroll
            for (int nt = 0; nt < 4; nt++)
                acc[mt][nt] = __builtin_amdgcn_mfma_f32_16x16x32_bf16(av[mt], bv[nt], acc[mt][nt], 0, 0, 0);
        __syncthreads();
    }
#pragma unroll
    for (int mt = 0; mt < 4; mt++) {
#pragma unroll
        for (int r = 0; r < 4; r++) {
            int row = row0 + wm + mt * 16 + (lane >> 4) * 4 + r;
            if (row >= M) continue;
#pragma unroll
            for (int nt = 0; nt < 4; nt++) {
                int col = wn + nt * 16 + r16;
                float v = acc[mt][nt][r];
                if (col < 64) {
                    out[(size_t)row * 64 + col] = v + bL1[col];
                } else {
                    out[(size_t)M * 64 + (size_t)row * 64 + (col - 64)] = v + bL2[col - 64];
                }
            }
        }
    }
}

// out[n][:] = relu(sum_{e in seg(n)} w_e * sup[src_e][:] + bias). One wave per node,
// lane holds 4 features -> one 512B gather reads a full bf16 row.
__global__ __launch_bounds__(256) void spmm_kernel(
    const unsigned short* __restrict__ sup, const int* __restrict__ rp,
    const int* __restrict__ esrc, const float* __restrict__ ew,
    const float* __restrict__ bias, unsigned short* __restrict__ out, int nnodes)
{
    int wid = threadIdx.x >> 6, lane = threadIdx.x & 63;
    int node = blockIdx.x * 4 + wid;
    if (node >= nnodes) return;
    int beg = rp[node], end = rp[node + 1];
    int f = lane * 4;
    float a0 = 0.f, a1 = 0.f, a2 = 0.f, a3 = 0.f;
    int e = beg;
    for (; e + 4 <= end; e += 4) {
        int s0 = esrc[e], s1 = esrc[e + 1], s2 = esrc[e + 2], s3 = esrc[e + 3];
        float w0 = ew[e], w1 = ew[e + 1], w2 = ew[e + 2], w3 = ew[e + 3];
        ushort4 r0 = *(const ushort4*)(sup + (size_t)s0 * 256 + f);
        ushort4 r1 = *(const ushort4*)(sup + (size_t)s1 * 256 + f);
        ushort4 r2 = *(const ushort4*)(sup + (size_t)s2 * 256 + f);
        ushort4 r3 = *(const ushort4*)(sup + (size_t)s3 * 256 + f);
        a0 += w0 * bf2f(r0.x) + w1 * bf2f(r1.x) + w2 * bf2f(r2.x) + w3 * bf2f(r3.x);
        a1 += w0 * bf2f(r0.y) + w1 * bf2f(r1.y) + w2 * bf2f(r2.y) + w3 * bf2f(r3.y);
        a2 += w0 * bf2f(r0.z) + w1 * bf2f(r1.z) + w2 * bf2f(r2.z) + w3 * bf2f(r3.z);
        a3 += w0 * bf2f(r0.w) + w1 * bf2f(r1.w) + w2 * bf2f(r2.w) + w3 * bf2f(r3.w);
    }
    for (; e < end; e++) {
        int s = esrc[e];
        float w = ew[e];
        ushort4 r = *(const ushort4*)(sup + (size_t)s * 256 + f);
        a0 += w * bf2f(r.x);
        a1 += w * bf2f(r.y);
        a2 += w * bf2f(r.z);
        a3 += w * bf2f(r.w);
    }
    a0 += bias[f + 0]; a1 += bias[f + 1]; a2 += bias[f + 2]; a3 += bias[f + 3];
    a0 = a0 > 0.f ? a0 : 0.f;
    a1 = a1 > 0.f ? a1 : 0.f;
    a2 = a2 > 0.f ? a2 : 0.f;
    a3 = a3 > 0.f ? a3 : 0.f;
    ushort4 o;
    o.x = f2bf(a0); o.y = f2bf(a1); o.z = f2bf(a2); o.w = f2bf(a3);
    *(ushort4*)(out + (size_t)node * 256 + f) = o;
}

extern "C" void kernel_launch(void* const* d_in, const int* in_sizes, int n_in,
                              void* d_out, int out_size, void* d_ws, size_t ws_size,
                              hipStream_t stream) {
    const float* x    = (const float*)d_in[0];
    const int*   esrc = (const int*)d_in[1];
    const int*   edst = (const int*)d_in[2];
    const float* ew   = (const float*)d_in[3];
    const float* W1   = (const float*)d_in[4];
    const float* b1   = (const float*)d_in[5];
    const float* W2   = (const float*)d_in[6];
    const float* b2   = (const float*)d_in[7];
    const float* WL1  = (const float*)d_in[8];
    const float* bL1  = (const float*)d_in[9];
    const float* WL2  = (const float*)d_in[10];
    const float* bL2  = (const float*)d_in[11];
    float* out = (float*)d_out;

    const int N = in_sizes[0] / 256;   // 100000
    const int E = in_sizes[1];         // 3200000

    char* ws = (char*)d_ws;
    size_t off = 0;
    auto alloc = [&](size_t bytes) -> void* {
        void* p = ws + off;
        off = (off + bytes + 255) & ~(size_t)255;
        return p;
    };
    int* rp              = (int*)alloc((size_t)(N + 1) * 4);
    unsigned short* W1t  = (unsigned short*)alloc((size_t)256 * 256 * 2);
    unsigned short* W2t  = (unsigned short*)alloc((size_t)256 * 256 * 2);
    unsigned short* WLt  = (unsigned short*)alloc((size_t)128 * 256 * 2);
    unsigned short* buf0 = (unsigned short*)alloc((size_t)N * 256 * 2);
    unsigned short* buf1 = (unsigned short*)alloc((size_t)N * 256 * 2);

    const int mblocks = (N + 127) / 128;

    rowptr_kernel<<<(N + 1 + 255) / 256, 256, 0, stream>>>(edst, rp, E, N);
    wconv_kernel<<<256, 256, 0, stream>>>(W1, W1t);
    wconv_kernel<<<256, 256, 0, stream>>>(W2, W2t);
    wlconv_kernel<<<128, 256, 0, stream>>>(WL1, WL2, WLt);

    gemm_kernel<float><<<dim3(mblocks, 2), 256, 0, stream>>>(x, W1t, buf0, N);
    spmm_kernel<<<(N + 3) / 4, 256, 0, stream>>>(buf0, rp, esrc, ew, b1, buf1, N);
    gemm_kernel<unsigned short><<<dim3(mblocks, 2), 256, 0, stream>>>(buf1, W2t, buf0, N);
    spmm_kernel<<<(N + 3) / 4, 256, 0, stream>>>(buf0, rp, esrc, ew, b2, buf1, N);
    head_kernel<<<dim3(mblocks, 1), 256, 0, stream>>>(buf1, WLt, bL1, bL2, out, N);
}

// Round 2
// 731.526 us; speedup vs baseline: 1.0040x; 1.0040x over previous
//
#include <hip/hip_runtime.h>
#include <hip/hip_bf16.h>
#include <type_traits>

typedef __attribute__((ext_vector_type(8))) short short8;
typedef __attribute__((ext_vector_type(4))) float f32x4;

__device__ inline unsigned short f2bf(float f) {
    union { float f; unsigned int u; } x; x.f = f;
    return (unsigned short)((x.u + 0x7fffu + ((x.u >> 16) & 1u)) >> 16);
}
__device__ inline float bflo(unsigned int u) { return __uint_as_float(u << 16); }
__device__ inline float bfhi(unsigned int u) { return __uint_as_float(u & 0xffff0000u); }

// rp[n] = lower_bound(dst, n) via boundary diff (dst sorted). One streamed pass.
__global__ void rowptr_kernel(const int* __restrict__ dst, int* __restrict__ rp,
                              int E, int N) {
    int e = blockIdx.x * blockDim.x + threadIdx.x;
    if (e >= E) return;
    int d1 = dst[e];
    int d0 = (e == 0) ? -1 : dst[e - 1];
    for (int n = d0 + 1; n <= d1; n++) rp[n] = e;
    if (e <= N) {                      // tail: nodes past the last dst value
        int dlast = dst[E - 1];
        if (e > dlast) rp[e] = E;
    }
}

// All weight conversions in one launch.
// blocks 0..255 -> W1t, 256..511 -> W2t, 512..639 -> WLt (WL1|WL2 stacked).
__global__ void prep_kernel(const float* __restrict__ W1, const float* __restrict__ W2,
                            const float* __restrict__ WL1, const float* __restrict__ WL2,
                            unsigned short* __restrict__ W1t, unsigned short* __restrict__ W2t,
                            unsigned short* __restrict__ WLt) {
    int b = blockIdx.x, k = threadIdx.x;
    if (b < 256) {
        W1t[(size_t)b * 256 + k] = f2bf(W1[(size_t)k * 256 + b]);
    } else if (b < 512) {
        int n = b - 256;
        W2t[(size_t)n * 256 + k] = f2bf(W2[(size_t)k * 256 + n]);
    } else {
        int c = b - 512;
        float v = (c < 64) ? WL1[(size_t)k * 64 + c] : WL2[(size_t)k * 64 + (c - 64)];
        WLt[(size_t)c * 256 + k] = f2bf(v);
    }
}

// C[M][256] (bf16) = A[M][256] @ Bt^T, Bt is [256][256] bf16 pre-transposed [n][k].
template <typename AT>
__global__ __launch_bounds__(256) void gemm_kernel(
    const AT* __restrict__ A, const unsigned short* __restrict__ Bt,
    unsigned short* __restrict__ C, int M)
{
    __shared__ __align__(16) unsigned short As[128][40]; // K-pad 32->40: 2-way bank alias (free)
    __shared__ __align__(16) unsigned short Bs[128][40];
    const int t = threadIdx.x;
    const int row0 = blockIdx.y * 128;   // grid transposed: col-halves adjacent in dispatch
    const int col0 = blockIdx.x * 128;
    const int wid = t >> 6, lane = t & 63;
    const int wm = (wid >> 1) * 64, wn = (wid & 1) * 64;
    const int qk = (lane >> 4) * 8, r16 = lane & 15;

    f32x4 acc[4][4];
#pragma unroll
    for (int i = 0; i < 4; i++)
#pragma unroll
        for (int j = 0; j < 4; j++) acc[i][j] = (f32x4){0.f, 0.f, 0.f, 0.f};

    for (int k0 = 0; k0 < 256; k0 += 32) {
#pragma unroll
        for (int i = 0; i < 2; i++) {
            int ch = t + i * 256;          // 512 granules of 8 elements
            int m = ch >> 2;               // 0..127
            int ko = (ch & 3) * 8;         // 0,8,16,24
            int row = row0 + m;
            uint4 pk;
            if (row < M) {
                if constexpr (std::is_same<AT, float>::value) {
                    const uint4* p = (const uint4*)(A + (size_t)row * 256 + k0 + ko);
                    uint4 u = p[0], v = p[1];
                    // round-half-up fp32->bf16 pack: 2.5 VALU ops/element
                    pk.x = ((u.x + 0x8000u) >> 16) | ((u.y + 0x8000u) & 0xffff0000u);
                    pk.y = ((u.z + 0x8000u) >> 16) | ((u.w + 0x8000u) & 0xffff0000u);
                    pk.z = ((v.x + 0x8000u) >> 16) | ((v.y + 0x8000u) & 0xffff0000u);
                    pk.w = ((v.z + 0x8000u) >> 16) | ((v.w + 0x8000u) & 0xffff0000u);
                } else {
                    pk = *(const uint4*)(A + (size_t)row * 256 + k0 + ko);
                }
            } else {
                pk = (uint4){0u, 0u, 0u, 0u};
            }
            *(uint4*)(&As[m][ko]) = pk;
            *(uint4*)(&Bs[m][ko]) = *(const uint4*)(Bt + (size_t)(col0 + m) * 256 + k0 + ko);
        }
        __syncthreads();
        short8 av[4], bv[4];
#pragma unroll
        for (int mt = 0; mt < 4; mt++) av[mt] = *(const short8*)(&As[wm + mt * 16 + r16][qk]);
#pragma unroll
        for (int nt = 0; nt < 4; nt++) bv[nt] = *(const short8*)(&Bs[wn + nt * 16 + r16][qk]);
#pragma unroll
        for (int mt = 0; mt < 4; mt++)
#pragma unroll
            for (int nt = 0; nt < 4; nt++)
                acc[mt][nt] = __builtin_amdgcn_mfma_f32_16x16x32_bf16(av[mt], bv[nt], acc[mt][nt], 0, 0, 0);
        __syncthreads();
    }
    // C/D layout: col = lane&15, row = (lane>>4)*4 + r  [measured m89/m91]
#pragma unroll
    for (int mt = 0; mt < 4; mt++) {
#pragma unroll
        for (int r = 0; r < 4; r++) {
            int row = row0 + wm + mt * 16 + (lane >> 4) * 4 + r;
            if (row >= M) continue;
#pragma unroll
            for (int nt = 0; nt < 4; nt++) {
                int col = col0 + wn + nt * 16 + r16;
                C[(size_t)row * 256 + col] = f2bf(acc[mt][nt][r]);
            }
        }
    }
}

// logits = h2 @ WLt^T + bias; cols 0..63 -> out0, 64..127 -> out1 (concatenated).
__global__ __launch_bounds__(256) void head_kernel(
    const unsigned short* __restrict__ A, const unsigned short* __restrict__ Bt,
    const float* __restrict__ bL1, const float* __restrict__ bL2,
    float* __restrict__ out, int M)
{
    __shared__ __align__(16) unsigned short As[128][40];
    __shared__ __align__(16) unsigned short Bs[128][40];
    const int t = threadIdx.x;
    const int row0 = blockIdx.x * 128;
    const int wid = t >> 6, lane = t & 63;
    const int wm = (wid >> 1) * 64, wn = (wid & 1) * 64;
    const int qk = (lane >> 4) * 8, r16 = lane & 15;

    f32x4 acc[4][4];
#pragma unroll
    for (int i = 0; i < 4; i++)
#pragma unroll
        for (int j = 0; j < 4; j++) acc[i][j] = (f32x4){0.f, 0.f, 0.f, 0.f};

    for (int k0 = 0; k0 < 256; k0 += 32) {
#pragma unroll
        for (int i = 0; i < 2; i++) {
            int ch = t + i * 256;
            int m = ch >> 2;
            int ko = (ch & 3) * 8;
            int row = row0 + m;
            uint4 pk = (uint4){0u, 0u, 0u, 0u};
            if (row < M) pk = *(const uint4*)(A + (size_t)row * 256 + k0 + ko);
            *(uint4*)(&As[m][ko]) = pk;
            *(uint4*)(&Bs[m][ko]) = *(const uint4*)(Bt + (size_t)m * 256 + k0 + ko);
        }
        __syncthreads();
        short8 av[4], bv[4];
#pragma unroll
        for (int mt = 0; mt < 4; mt++) av[mt] = *(const short8*)(&As[wm + mt * 16 + r16][qk]);
#pragma unroll
        for (int nt = 0; nt < 4; nt++) bv[nt] = *(const short8*)(&Bs[wn + nt * 16 + r16][qk]);
#pragma unroll
        for (int mt = 0; mt < 4; mt++)
#pragma unroll
            for (int nt = 0; nt < 4; nt++)
                acc[mt][nt] = __builtin_amdgcn_mfma_f32_16x16x32_bf16(av[mt], bv[nt], acc[mt][nt], 0, 0, 0);
        __syncthreads();
    }
#pragma unroll
    for (int mt = 0; mt < 4; mt++) {
#pragma unroll
        for (int r = 0; r < 4; r++) {
            int row = row0 + wm + mt * 16 + (lane >> 4) * 4 + r;
            if (row >= M) continue;
#pragma unroll
            for (int nt = 0; nt < 4; nt++) {
                int col = wn + nt * 16 + r16;
                float v = acc[mt][nt][r];
                if (col < 64) {
                    out[(size_t)row * 64 + col] = v + bL1[col];
                } else {
                    out[(size_t)M * 64 + (size_t)row * 64 + (col - 64)] = v + bL2[col - 64];
                }
            }
        }
    }
}

__device__ inline void acc8(float* a, uint4 r, float w) {
    a[0] += w * bflo(r.x); a[1] += w * bfhi(r.x);
    a[2] += w * bflo(r.y); a[3] += w * bfhi(r.y);
    a[4] += w * bflo(r.z); a[5] += w * bfhi(r.z);
    a[6] += w * bflo(r.w); a[7] += w * bfhi(r.w);
}

// out[n][:] = relu(sum_e w_e * sup[src_e][:] + bias). One wave per node.
// Wave split into two 32-lane groups; group g handles edge subset, lane holds
// 8 features (16B loads -> 1024B/instr = 2 rows). Cross-group combine by shfl_xor(32).
__global__ __launch_bounds__(256) void spmm_kernel(
    const unsigned short* __restrict__ sup, const int* __restrict__ rp,
    const int* __restrict__ esrc, const float* __restrict__ ew,
    const float* __restrict__ bias, unsigned short* __restrict__ out, int nnodes)
{
    const int wid = threadIdx.x >> 6, lane = threadIdx.x & 63;
    const int node = blockIdx.x * 4 + wid;
    if (node >= nnodes) return;
    const int g = lane >> 5;
    const int f8 = (lane & 31) * 8;
    const unsigned short* supf = sup + f8;
    const int beg = rp[node], end = rp[node + 1];

    float a[8];
#pragma unroll
    for (int i = 0; i < 8; i++) a[i] = 0.f;

    int e = beg;
    // software pipeline: prefetch edge meta for the next 8-edge chunk
    int ps0 = 0, ps1 = 0, ps2 = 0, ps3 = 0;
    float pw0 = 0.f, pw1 = 0.f, pw2 = 0.f, pw3 = 0.f;
    if (e + 8 <= end) {
        int eb = e + 4 * g;   // group g takes contiguous 4 edges
        ps0 = esrc[eb]; ps1 = esrc[eb + 1]; ps2 = esrc[eb + 2]; ps3 = esrc[eb + 3];
        pw0 = ew[eb];   pw1 = ew[eb + 1];   pw2 = ew[eb + 2];   pw3 = ew[eb + 3];
    }
    while (e + 8 <= end) {
        const int s0 = ps0, s1 = ps1, s2 = ps2, s3 = ps3;
        const float w0 = pw0, w1 = pw1, w2 = pw2, w3 = pw3;
        const int en = e + 8;
        if (en + 8 <= end) {
            int eb = en + 4 * g;
            ps0 = esrc[eb]; ps1 = esrc[eb + 1]; ps2 = esrc[eb + 2]; ps3 = esrc[eb + 3];
            pw0 = ew[eb];   pw1 = ew[eb + 1];   pw2 = ew[eb + 2];   pw3 = ew[eb + 3];
        }
        const uint4 r0 = *(const uint4*)(supf + (size_t)s0 * 256);
        const uint4 r1 = *(const uint4*)(supf + (size_t)s1 * 256);
        const uint4 r2 = *(const uint4*)(supf + (size_t)s2 * 256);
        const uint4 r3 = *(const uint4*)(supf + (size_t)s3 * 256);
        acc8(a, r0, w0);
        acc8(a, r1, w1);
        acc8(a, r2, w2);
        acc8(a, r3, w3);
        e = en;
    }
    for (; e + 2 <= end; e += 2) {       // pair tail: one edge per group
        const int s = esrc[e + g];
        const float w = ew[e + g];
        const uint4 r = *(const uint4*)(supf + (size_t)s * 256);
        acc8(a, r, w);
    }
    if (e < end && g == 0) {             // odd leftover edge: group 0 only
        const int s = esrc[e];
        const float w = ew[e];
        const uint4 r = *(const uint4*)(supf + (size_t)s * 256);
        acc8(a, r, w);
    }
    // combine the two edge-groups (same features live in lane L and L+32)
#pragma unroll
    for (int i = 0; i < 8; i++) a[i] += __shfl_xor(a[i], 32);

    if (g == 0) {
        const float4 b0 = *(const float4*)(bias + f8);
        const float4 b1 = *(const float4*)(bias + f8 + 4);
        a[0] += b0.x; a[1] += b0.y; a[2] += b0.z; a[3] += b0.w;
        a[4] += b1.x; a[5] += b1.y; a[6] += b1.z; a[7] += b1.w;
#pragma unroll
        for (int i = 0; i < 8; i++) a[i] = a[i] > 0.f ? a[i] : 0.f;
        uint4 o;
        o.x = (unsigned int)f2bf(a[0]) | ((unsigned int)f2bf(a[1]) << 16);
        o.y = (unsigned int)f2bf(a[2]) | ((unsigned int)f2bf(a[3]) << 16);
        o.z = (unsigned int)f2bf(a[4]) | ((unsigned int)f2bf(a[5]) << 16);
        o.w = (unsigned int)f2bf(a[6]) | ((unsigned int)f2bf(a[7]) << 16);
        *(uint4*)(out + (size_t)node * 256 + f8) = o;
    }
}

extern "C" void kernel_launch(void* const* d_in, const int* in_sizes, int n_in,
                              void* d_out, int out_size, void* d_ws, size_t ws_size,
                              hipStream_t stream) {
    const float* x    = (const float*)d_in[0];
    const int*   esrc = (const int*)d_in[1];
    const int*   edst = (const int*)d_in[2];
    const float* ew   = (const float*)d_in[3];
    const float* W1   = (const float*)d_in[4];
    const float* b1   = (const float*)d_in[5];
    const float* W2   = (const float*)d_in[6];
    const float* b2   = (const float*)d_in[7];
    const float* WL1  = (const float*)d_in[8];
    const float* bL1  = (const float*)d_in[9];
    const float* WL2  = (const float*)d_in[10];
    const float* bL2  = (const float*)d_in[11];
    float* out = (float*)d_out;

    const int N = in_sizes[0] / 256;   // 100000
    const int E = in_sizes[1];         // 3200000

    char* ws = (char*)d_ws;
    size_t off = 0;
    auto alloc = [&](size_t bytes) -> void* {
        void* p = ws + off;
        off = (off + bytes + 255) & ~(size_t)255;
        return p;
    };
    int* rp              = (int*)alloc((size_t)(N + 1) * 4);
    unsigned short* W1t  = (unsigned short*)alloc((size_t)256 * 256 * 2);
    unsigned short* W2t  = (unsigned short*)alloc((size_t)256 * 256 * 2);
    unsigned short* WLt  = (unsigned short*)alloc((size_t)128 * 256 * 2);
    unsigned short* buf0 = (unsigned short*)alloc((size_t)N * 256 * 2);
    unsigned short* buf1 = (unsigned short*)alloc((size_t)N * 256 * 2);

    const int mblocks = (N + 127) / 128;

    rowptr_kernel<<<(E + 255) / 256, 256, 0, stream>>>(edst, rp, E, N);
    prep_kernel<<<640, 256, 0, stream>>>(W1, W2, WL1, WL2, W1t, W2t, WLt);

    gemm_kernel<float><<<dim3(2, mblocks), 256, 0, stream>>>(x, W1t, buf0, N);
    spmm_kernel<<<(N + 3) / 4, 256, 0, stream>>>(buf0, rp, esrc, ew, b1, buf1, N);
    gemm_kernel<unsigned short><<<dim3(2, mblocks), 256, 0, stream>>>(buf1, W2t, buf0, N);
    spmm_kernel<<<(N + 3) / 4, 256, 0, stream>>>(buf0, rp, esrc, ew, b2, buf1, N);
    head_kernel<<<dim3(mblocks, 1), 256, 0, stream>>>(buf1, WLt, bL1, bL2, out, N);
}

// Round 3
// 652.481 us; speedup vs baseline: 1.1256x; 1.1211x over previous
//
#include <hip/hip_runtime.h>
#include <hip/hip_bf16.h>
#include <type_traits>

typedef __attribute__((ext_vector_type(8))) short short8;
typedef __attribute__((ext_vector_type(4))) float f32x4;
typedef __attribute__((ext_vector_type(2))) float f32x2;

__device__ inline unsigned short f2bf(float f) {
    union { float f; unsigned int u; } x; x.f = f;
    return (unsigned short)((x.u + 0x7fffu + ((x.u >> 16) & 1u)) >> 16);
}
__device__ inline float bflo(unsigned int u) { return __uint_as_float(u << 16); }
__device__ inline float bfhi(unsigned int u) { return __uint_as_float(u & 0xffff0000u); }

// rp[n] = lower_bound(dst, n) via boundary diff (dst sorted). One streamed pass.
__global__ void rowptr_kernel(const int* __restrict__ dst, int* __restrict__ rp,
                              int E, int N) {
    int e = blockIdx.x * blockDim.x + threadIdx.x;
    if (e >= E) return;
    int d1 = dst[e];
    int d0 = (e == 0) ? -1 : dst[e - 1];
    for (int n = d0 + 1; n <= d1; n++) rp[n] = e;
    if (e <= N) {                      // tail: nodes past the last dst value
        int dlast = dst[E - 1];
        if (e > dlast) rp[e] = E;
    }
}

// All weight conversions in one launch.
// blocks 0..255 -> W1t, 256..511 -> W2t, 512..639 -> WLt (WL1|WL2 stacked).
__global__ void prep_kernel(const float* __restrict__ W1, const float* __restrict__ W2,
                            const float* __restrict__ WL1, const float* __restrict__ WL2,
                            unsigned short* __restrict__ W1t, unsigned short* __restrict__ W2t,
                            unsigned short* __restrict__ WLt) {
    int b = blockIdx.x, k = threadIdx.x;
    if (b < 256) {
        W1t[(size_t)b * 256 + k] = f2bf(W1[(size_t)k * 256 + b]);
    } else if (b < 512) {
        int n = b - 256;
        W2t[(size_t)n * 256 + k] = f2bf(W2[(size_t)k * 256 + n]);
    } else {
        int c = b - 512;
        float v = (c < 64) ? WL1[(size_t)k * 64 + c] : WL2[(size_t)k * 64 + (c - 64)];
        WLt[(size_t)c * 256 + k] = f2bf(v);
    }
}

// C[M][256] = A[M][256] @ Bt^T, Bt is [256][256] bf16 pre-transposed [n][k].
// AT: float (converted inline) or unsigned short (bf16). OT: unsigned short (bf16) or
// unsigned char (fp8 e4m3, HW cvt_pk encode).
template <typename AT, typename OT>
__global__ __launch_bounds__(256) void gemm_kernel(
    const AT* __restrict__ A, const unsigned short* __restrict__ Bt,
    OT* __restrict__ C, int M)
{
    __shared__ __align__(16) unsigned short As[128][40]; // K-pad 32->40: 2-way bank alias (free)
    __shared__ __align__(16) unsigned short Bs[128][40];
    const int t = threadIdx.x;
    const int row0 = blockIdx.y * 128;
    const int col0 = blockIdx.x * 128;
    const int wid = t >> 6, lane = t & 63;
    const int wm = (wid >> 1) * 64, wn = (wid & 1) * 64;
    const int qk = (lane >> 4) * 8, r16 = lane & 15;

    f32x4 acc[4][4];
#pragma unroll
    for (int i = 0; i < 4; i++)
#pragma unroll
        for (int j = 0; j < 4; j++) acc[i][j] = (f32x4){0.f, 0.f, 0.f, 0.f};

    for (int k0 = 0; k0 < 256; k0 += 32) {
#pragma unroll
        for (int i = 0; i < 2; i++) {
            int ch = t + i * 256;          // 512 granules of 8 elements
            int m = ch >> 2;               // 0..127
            int ko = (ch & 3) * 8;         // 0,8,16,24
            int row = row0 + m;
            uint4 pk;
            if (row < M) {
                if constexpr (std::is_same<AT, float>::value) {
                    const uint4* p = (const uint4*)(A + (size_t)row * 256 + k0 + ko);
                    uint4 u = p[0], v = p[1];
                    // round-half-up fp32->bf16 pack
                    pk.x = ((u.x + 0x8000u) >> 16) | ((u.y + 0x8000u) & 0xffff0000u);
                    pk.y = ((u.z + 0x8000u) >> 16) | ((u.w + 0x8000u) & 0xffff0000u);
                    pk.z = ((v.x + 0x8000u) >> 16) | ((v.y + 0x8000u) & 0xffff0000u);
                    pk.w = ((v.z + 0x8000u) >> 16) | ((v.w + 0x8000u) & 0xffff0000u);
                } else {
                    pk = *(const uint4*)(A + (size_t)row * 256 + k0 + ko);
                }
            } else {
                pk = (uint4){0u, 0u, 0u, 0u};
            }
            *(uint4*)(&As[m][ko]) = pk;
            *(uint4*)(&Bs[m][ko]) = *(const uint4*)(Bt + (size_t)(col0 + m) * 256 + k0 + ko);
        }
        __syncthreads();
        short8 av[4], bv[4];
#pragma unroll
        for (int mt = 0; mt < 4; mt++) av[mt] = *(const short8*)(&As[wm + mt * 16 + r16][qk]);
#pragma unroll
        for (int nt = 0; nt < 4; nt++) bv[nt] = *(const short8*)(&Bs[wn + nt * 16 + r16][qk]);
#pragma unroll
        for (int mt = 0; mt < 4; mt++)
#pragma unroll
            for (int nt = 0; nt < 4; nt++)
                acc[mt][nt] = __builtin_amdgcn_mfma_f32_16x16x32_bf16(av[mt], bv[nt], acc[mt][nt], 0, 0, 0);
        __syncthreads();
    }
    // C/D layout: col = lane&15, row = (lane>>4)*4 + r  [measured m89/m91]
#pragma unroll
    for (int mt = 0; mt < 4; mt++) {
#pragma unroll
        for (int r = 0; r < 4; r++) {
            int row = row0 + wm + mt * 16 + (lane >> 4) * 4 + r;
            if (row >= M) continue;
#pragma unroll
            for (int nt = 0; nt < 4; nt++) {
                int col = col0 + wn + nt * 16 + r16;
                float v = acc[mt][nt][r];
                if constexpr (std::is_same<OT, unsigned char>::value) {
                    unsigned int p = (unsigned int)__builtin_amdgcn_cvt_pk_fp8_f32(v, v, 0, false);
                    C[(size_t)row * 256 + col] = (unsigned char)(p & 0xffu);
                } else {
                    C[(size_t)row * 256 + col] = f2bf(v);
                }
            }
        }
    }
}

// logits = h2 @ WLt^T + bias; cols 0..63 -> out0, 64..127 -> out1 (concatenated).
__global__ __launch_bounds__(256) void head_kernel(
    const unsigned short* __restrict__ A, const unsigned short* __restrict__ Bt,
    const float* __restrict__ bL1, const float* __restrict__ bL2,
    float* __restrict__ out, int M)
{
    __shared__ __align__(16) unsigned short As[128][40];
    __shared__ __align__(16) unsigned short Bs[128][40];
    const int t = threadIdx.x;
    const int row0 = blockIdx.x * 128;
    const int wid = t >> 6, lane = t & 63;
    const int wm = (wid >> 1) * 64, wn = (wid & 1) * 64;
    const int qk = (lane >> 4) * 8, r16 = lane & 15;

    f32x4 acc[4][4];
#pragma unroll
    for (int i = 0; i < 4; i++)
#pragma unroll
        for (int j = 0; j < 4; j++) acc[i][j] = (f32x4){0.f, 0.f, 0.f, 0.f};

    for (int k0 = 0; k0 < 256; k0 += 32) {
#pragma unroll
        for (int i = 0; i < 2; i++) {
            int ch = t + i * 256;
            int m = ch >> 2;
            int ko = (ch & 3) * 8;
            int row = row0 + m;
            uint4 pk = (uint4){0u, 0u, 0u, 0u};
            if (row < M) pk = *(const uint4*)(A + (size_t)row * 256 + k0 + ko);
            *(uint4*)(&As[m][ko]) = pk;
            *(uint4*)(&Bs[m][ko]) = *(const uint4*)(Bt + (size_t)m * 256 + k0 + ko);
        }
        __syncthreads();
        short8 av[4], bv[4];
#pragma unroll
        for (int mt = 0; mt < 4; mt++) av[mt] = *(const short8*)(&As[wm + mt * 16 + r16][qk]);
#pragma unroll
        for (int nt = 0; nt < 4; nt++) bv[nt] = *(const short8*)(&Bs[wn + nt * 16 + r16][qk]);
#pragma unroll
        for (int mt = 0; mt < 4; mt++)
#pragma unroll
            for (int nt = 0; nt < 4; nt++)
                acc[mt][nt] = __builtin_amdgcn_mfma_f32_16x16x32_bf16(av[mt], bv[nt], acc[mt][nt], 0, 0, 0);
        __syncthreads();
    }
#pragma unroll
    for (int mt = 0; mt < 4; mt++) {
#pragma unroll
        for (int r = 0; r < 4; r++) {
            int row = row0 + wm + mt * 16 + (lane >> 4) * 4 + r;
            if (row >= M) continue;
#pragma unroll
            for (int nt = 0; nt < 4; nt++) {
                int col = wn + nt * 16 + r16;
                float v = acc[mt][nt][r];
                if (col < 64) {
                    out[(size_t)row * 64 + col] = v + bL1[col];
                } else {
                    out[(size_t)M * 64 + (size_t)row * 64 + (col - 64)] = v + bL2[col - 64];
                }
            }
        }
    }
}

__device__ inline void acc8(float* a, uint4 r, float w) {
    a[0] += w * bflo(r.x); a[1] += w * bfhi(r.x);
    a[2] += w * bflo(r.y); a[3] += w * bfhi(r.y);
    a[4] += w * bflo(r.z); a[5] += w * bfhi(r.z);
    a[6] += w * bflo(r.w); a[7] += w * bfhi(r.w);
}
__device__ inline void acc8f8(float* a, uint2 r, float w) {
    f32x2 p0 = __builtin_amdgcn_cvt_pk_f32_fp8((int)r.x, false); // bytes 0,1
    f32x2 p1 = __builtin_amdgcn_cvt_pk_f32_fp8((int)r.x, true);  // bytes 2,3
    f32x2 p2 = __builtin_amdgcn_cvt_pk_f32_fp8((int)r.y, false);
    f32x2 p3 = __builtin_amdgcn_cvt_pk_f32_fp8((int)r.y, true);
    a[0] += w * p0.x; a[1] += w * p0.y; a[2] += w * p1.x; a[3] += w * p1.y;
    a[4] += w * p2.x; a[5] += w * p2.y; a[6] += w * p3.x; a[7] += w * p3.y;
}

// bf16-row SPMM: out[n][:] = relu(sum_e w_e * sup[src_e][:] + bias).
// One wave per node; two 32-lane groups, each group one edge per step, lane holds
// 8 features (16B) -> one load instr = 2 x 512B rows. Combine via shfl_xor(32).
__global__ __launch_bounds__(256) void spmm_kernel(
    const unsigned short* __restrict__ sup, const int* __restrict__ rp,
    const int* __restrict__ esrc, const float* __restrict__ ew,
    const float* __restrict__ bias, unsigned short* __restrict__ out, int nnodes)
{
    const int wid = threadIdx.x >> 6, lane = threadIdx.x & 63;
    const int node = blockIdx.x * 4 + wid;
    if (node >= nnodes) return;
    const int g = lane >> 5;
    const int f8 = (lane & 31) * 8;
    const unsigned short* supf = sup + f8;
    const int beg = rp[node], end = rp[node + 1];

    float a[8];
#pragma unroll
    for (int i = 0; i < 8; i++) a[i] = 0.f;

    int e = beg;
    for (; e + 4 <= end; e += 4) {       // 2 edges per group in flight
        const int eb = e + g * 2;
        const int s0 = esrc[eb], s1 = esrc[eb + 1];
        const float w0 = ew[eb], w1 = ew[eb + 1];
        const uint4 r0 = *(const uint4*)(supf + (size_t)s0 * 256);
        const uint4 r1 = *(const uint4*)(supf + (size_t)s1 * 256);
        acc8(a, r0, w0);
        acc8(a, r1, w1);
    }
    for (; e + 2 <= end; e += 2) {
        const int s = esrc[e + g];
        const float w = ew[e + g];
        const uint4 r = *(const uint4*)(supf + (size_t)s * 256);
        acc8(a, r, w);
    }
    if (e < end && g == 0) {
        const int s = esrc[e];
        const float w = ew[e];
        const uint4 r = *(const uint4*)(supf + (size_t)s * 256);
        acc8(a, r, w);
    }
#pragma unroll
    for (int i = 0; i < 8; i++) a[i] += __shfl_xor(a[i], 32);

    if (g == 0) {
        const float4 b0 = *(const float4*)(bias + f8);
        const float4 b1 = *(const float4*)(bias + f8 + 4);
        a[0] += b0.x; a[1] += b0.y; a[2] += b0.z; a[3] += b0.w;
        a[4] += b1.x; a[5] += b1.y; a[6] += b1.z; a[7] += b1.w;
#pragma unroll
        for (int i = 0; i < 8; i++) a[i] = a[i] > 0.f ? a[i] : 0.f;
        uint4 o;
        o.x = (unsigned int)f2bf(a[0]) | ((unsigned int)f2bf(a[1]) << 16);
        o.y = (unsigned int)f2bf(a[2]) | ((unsigned int)f2bf(a[3]) << 16);
        o.z = (unsigned int)f2bf(a[4]) | ((unsigned int)f2bf(a[5]) << 16);
        o.w = (unsigned int)f2bf(a[6]) | ((unsigned int)f2bf(a[7]) << 16);
        *(uint4*)(out + (size_t)node * 256 + f8) = o;
    }
}

// fp8-row SPMM: identical structure, rows are 256B e4m3; lane holds 8 features (8B).
__global__ __launch_bounds__(256) void spmm_fp8_kernel(
    const unsigned char* __restrict__ sup, const int* __restrict__ rp,
    const int* __restrict__ esrc, const float* __restrict__ ew,
    const float* __restrict__ bias, unsigned short* __restrict__ out, int nnodes)
{
    const int wid = threadIdx.x >> 6, lane = threadIdx.x & 63;
    const int node = blockIdx.x * 4 + wid;
    if (node >= nnodes) return;
    const int g = lane >> 5;
    const int f8 = (lane & 31) * 8;
    const unsigned char* supf = sup + f8;
    const int beg = rp[node], end = rp[node + 1];

    float a[8];
#pragma unroll
    for (int i = 0; i < 8; i++) a[i] = 0.f;

    int e = beg;
    for (; e + 4 <= end; e += 4) {
        const int eb = e + g * 2;
        const int s0 = esrc[eb], s1 = esrc[eb + 1];
        const float w0 = ew[eb], w1 = ew[eb + 1];
        const uint2 r0 = *(const uint2*)(supf + (size_t)s0 * 256);
        const uint2 r1 = *(const uint2*)(supf + (size_t)s1 * 256);
        acc8f8(a, r0, w0);
        acc8f8(a, r1, w1);
    }
    for (; e + 2 <= end; e += 2) {
        const int s = esrc[e + g];
        const float w = ew[e + g];
        const uint2 r = *(const uint2*)(supf + (size_t)s * 256);
        acc8f8(a, r, w);
    }
    if (e < end && g == 0) {
        const int s = esrc[e];
        const float w = ew[e];
        const uint2 r = *(const uint2*)(supf + (size_t)s * 256);
        acc8f8(a, r, w);
    }
#pragma unroll
    for (int i = 0; i < 8; i++) a[i] += __shfl_xor(a[i], 32);

    if (g == 0) {
        const float4 b0 = *(const float4*)(bias + f8);
        const float4 b1 = *(const float4*)(bias + f8 + 4);
        a[0] += b0.x; a[1] += b0.y; a[2] += b0.z; a[3] += b0.w;
        a[4] += b1.x; a[5] += b1.y; a[6] += b1.z; a[7] += b1.w;
#pragma unroll
        for (int i = 0; i < 8; i++) a[i] = a[i] > 0.f ? a[i] : 0.f;
        uint4 o;
        o.x = (unsigned int)f2bf(a[0]) | ((unsigned int)f2bf(a[1]) << 16);
        o.y = (unsigned int)f2bf(a[2]) | ((unsigned int)f2bf(a[3]) << 16);
        o.z = (unsigned int)f2bf(a[4]) | ((unsigned int)f2bf(a[5]) << 16);
        o.w = (unsigned int)f2bf(a[6]) | ((unsigned int)f2bf(a[7]) << 16);
        *(uint4*)(out + (size_t)node * 256 + f8) = o;
    }
}

extern "C" void kernel_launch(void* const* d_in, const int* in_sizes, int n_in,
                              void* d_out, int out_size, void* d_ws, size_t ws_size,
                              hipStream_t stream) {
    const float* x    = (const float*)d_in[0];
    const int*   esrc = (const int*)d_in[1];
    const int*   edst = (const int*)d_in[2];
    const float* ew   = (const float*)d_in[3];
    const float* W1   = (const float*)d_in[4];
    const float* b1   = (const float*)d_in[5];
    const float* W2   = (const float*)d_in[6];
    const float* b2   = (const float*)d_in[7];
    const float* WL1  = (const float*)d_in[8];
    const float* bL1  = (const float*)d_in[9];
    const float* WL2  = (const float*)d_in[10];
    const float* bL2  = (const float*)d_in[11];
    float* out = (float*)d_out;

    const int N = in_sizes[0] / 256;   // 100000
    const int E = in_sizes[1];         // 3200000

    char* ws = (char*)d_ws;
    size_t off = 0;
    auto alloc = [&](size_t bytes) -> void* {
        void* p = ws + off;
        off = (off + bytes + 511) & ~(size_t)511;   // 512B-align: rows stay line-aligned
        return p;
    };
    int* rp              = (int*)alloc((size_t)(N + 1) * 4);
    unsigned short* W1t  = (unsigned short*)alloc((size_t)256 * 256 * 2);
    unsigned short* W2t  = (unsigned short*)alloc((size_t)256 * 256 * 2);
    unsigned short* WLt  = (unsigned short*)alloc((size_t)128 * 256 * 2);
    void* buf0           = alloc((size_t)N * 256 * 2);   // fp8 support1 / bf16 support2
    unsigned short* buf1 = (unsigned short*)alloc((size_t)N * 256 * 2);

    const int mblocks = (N + 127) / 128;

    rowptr_kernel<<<(E + 255) / 256, 256, 0, stream>>>(edst, rp, E, N);
    prep_kernel<<<640, 256, 0, stream>>>(W1, W2, WL1, WL2, W1t, W2t, WLt);

    // layer 1: support in fp8 e4m3 (halves SPMM gather traffic)
    gemm_kernel<float, unsigned char><<<dim3(2, mblocks), 256, 0, stream>>>(
        x, W1t, (unsigned char*)buf0, N);
    spmm_fp8_kernel<<<(N + 3) / 4, 256, 0, stream>>>(
        (const unsigned char*)buf0, rp, esrc, ew, b1, buf1, N);
    // layer 2: support in bf16 (protect error budget)
    gemm_kernel<unsigned short, unsigned short><<<dim3(2, mblocks), 256, 0, stream>>>(
        buf1, W2t, (unsigned short*)buf0, N);
    spmm_kernel<<<(N + 3) / 4, 256, 0, stream>>>(
        (const unsigned short*)buf0, rp, esrc, ew, b2, buf1, N);
    head_kernel<<<dim3(mblocks, 1), 256, 0, stream>>>(buf1, WLt, bL1, bL2, out, N);
}

// Round 4
// 519.543 us; speedup vs baseline: 1.4137x; 1.2559x over previous
//
#include <hip/hip_runtime.h>
#include <hip/hip_bf16.h>
#include <type_traits>

typedef __attribute__((ext_vector_type(8))) short short8;
typedef __attribute__((ext_vector_type(4))) float f32x4;
typedef __attribute__((ext_vector_type(2))) float f32x2;

__device__ inline unsigned short f2bf(float f) {
    union { float f; unsigned int u; } x; x.f = f;
    return (unsigned short)((x.u + 0x7fffu + ((x.u >> 16) & 1u)) >> 16);
}
__device__ inline float bflo(unsigned int u) { return __uint_as_float(u << 16); }
__device__ inline float bfhi(unsigned int u) { return __uint_as_float(u & 0xffff0000u); }

// rp[n] = lower_bound(dst, n) via boundary diff (dst sorted). One streamed pass.
__global__ void rowptr_kernel(const int* __restrict__ dst, int* __restrict__ rp,
                              int E, int N) {
    int e = blockIdx.x * blockDim.x + threadIdx.x;
    if (e >= E) return;
    int d1 = dst[e];
    int d0 = (e == 0) ? -1 : dst[e - 1];
    for (int n = d0 + 1; n <= d1; n++) rp[n] = e;
    if (e <= N) {                      // tail: nodes past the last dst value
        int dlast = dst[E - 1];
        if (e > dlast) rp[e] = E;
    }
}

// All weight conversions in one launch.
// blocks 0..255 -> W1t, 256..511 -> W2t, 512..639 -> WLt (WL1|WL2 stacked).
__global__ void prep_kernel(const float* __restrict__ W1, const float* __restrict__ W2,
                            const float* __restrict__ WL1, const float* __restrict__ WL2,
                            unsigned short* __restrict__ W1t, unsigned short* __restrict__ W2t,
                            unsigned short* __restrict__ WLt) {
    int b = blockIdx.x, k = threadIdx.x;
    if (b < 256) {
        W1t[(size_t)b * 256 + k] = f2bf(W1[(size_t)k * 256 + b]);
    } else if (b < 512) {
        int n = b - 256;
        W2t[(size_t)n * 256 + k] = f2bf(W2[(size_t)k * 256 + n]);
    } else {
        int c = b - 512;
        float v = (c < 64) ? WL1[(size_t)k * 64 + c] : WL2[(size_t)k * 64 + (c - 64)];
        WLt[(size_t)c * 256 + k] = f2bf(v);
    }
}

// C[M][256] = A[M][256] @ Bt^T, Bt is [256][256] bf16 pre-transposed [n][k].
// AT: float (converted inline) or unsigned short (bf16). OT: unsigned short (bf16) or
// unsigned char (fp8 e4m3, HW cvt_pk encode).
template <typename AT, typename OT>
__global__ __launch_bounds__(256) void gemm_kernel(
    const AT* __restrict__ A, const unsigned short* __restrict__ Bt,
    OT* __restrict__ C, int M)
{
    __shared__ __align__(16) unsigned short As[128][40]; // K-pad 32->40: 2-way bank alias (free)
    __shared__ __align__(16) unsigned short Bs[128][40];
    const int t = threadIdx.x;
    const int row0 = blockIdx.y * 128;
    const int col0 = blockIdx.x * 128;
    const int wid = t >> 6, lane = t & 63;
    const int wm = (wid >> 1) * 64, wn = (wid & 1) * 64;
    const int qk = (lane >> 4) * 8, r16 = lane & 15;

    f32x4 acc[4][4];
#pragma unroll
    for (int i = 0; i < 4; i++)
#pragma unroll
        for (int j = 0; j < 4; j++) acc[i][j] = (f32x4){0.f, 0.f, 0.f, 0.f};

    for (int k0 = 0; k0 < 256; k0 += 32) {
#pragma unroll
        for (int i = 0; i < 2; i++) {
            int ch = t + i * 256;          // 512 granules of 8 elements
            int m = ch >> 2;               // 0..127
            int ko = (ch & 3) * 8;         // 0,8,16,24
            int row = row0 + m;
            uint4 pk;
            if (row < M) {
                if constexpr (std::is_same<AT, float>::value) {
                    const uint4* p = (const uint4*)(A + (size_t)row * 256 + k0 + ko);
                    uint4 u = p[0], v = p[1];
                    // round-half-up fp32->bf16 pack
                    pk.x = ((u.x + 0x8000u) >> 16) | ((u.y + 0x8000u) & 0xffff0000u);
                    pk.y = ((u.z + 0x8000u) >> 16) | ((u.w + 0x8000u) & 0xffff0000u);
                    pk.z = ((v.x + 0x8000u) >> 16) | ((v.y + 0x8000u) & 0xffff0000u);
                    pk.w = ((v.z + 0x8000u) >> 16) | ((v.w + 0x8000u) & 0xffff0000u);
                } else {
                    pk = *(const uint4*)(A + (size_t)row * 256 + k0 + ko);
                }
            } else {
                pk = (uint4){0u, 0u, 0u, 0u};
            }
            *(uint4*)(&As[m][ko]) = pk;
            *(uint4*)(&Bs[m][ko]) = *(const uint4*)(Bt + (size_t)(col0 + m) * 256 + k0 + ko);
        }
        __syncthreads();
        short8 av[4], bv[4];
#pragma unroll
        for (int mt = 0; mt < 4; mt++) av[mt] = *(const short8*)(&As[wm + mt * 16 + r16][qk]);
#pragma unroll
        for (int nt = 0; nt < 4; nt++) bv[nt] = *(const short8*)(&Bs[wn + nt * 16 + r16][qk]);
#pragma unroll
        for (int mt = 0; mt < 4; mt++)
#pragma unroll
            for (int nt = 0; nt < 4; nt++)
                acc[mt][nt] = __builtin_amdgcn_mfma_f32_16x16x32_bf16(av[mt], bv[nt], acc[mt][nt], 0, 0, 0);
        __syncthreads();
    }
    // C/D layout: col = lane&15, row = (lane>>4)*4 + r  [measured m89/m91]
#pragma unroll
    for (int mt = 0; mt < 4; mt++) {
#pragma unroll
        for (int r = 0; r < 4; r++) {
            int row = row0 + wm + mt * 16 + (lane >> 4) * 4 + r;
            if (row >= M) continue;
#pragma unroll
            for (int nt = 0; nt < 4; nt++) {
                int col = col0 + wn + nt * 16 + r16;
                float v = acc[mt][nt][r];
                if constexpr (std::is_same<OT, unsigned char>::value) {
                    unsigned int p = (unsigned int)__builtin_amdgcn_cvt_pk_fp8_f32(v, v, 0, false);
                    C[(size_t)row * 256 + col] = (unsigned char)(p & 0xffu);
                } else {
                    C[(size_t)row * 256 + col] = f2bf(v);
                }
            }
        }
    }
}

// logits = h2 @ WLt^T + bias; cols 0..63 -> out0, 64..127 -> out1 (concatenated).
__global__ __launch_bounds__(256) void head_kernel(
    const unsigned short* __restrict__ A, const unsigned short* __restrict__ Bt,
    const float* __restrict__ bL1, const float* __restrict__ bL2,
    float* __restrict__ out, int M)
{
    __shared__ __align__(16) unsigned short As[128][40];
    __shared__ __align__(16) unsigned short Bs[128][40];
    const int t = threadIdx.x;
    const int row0 = blockIdx.x * 128;
    const int wid = t >> 6, lane = t & 63;
    const int wm = (wid >> 1) * 64, wn = (wid & 1) * 64;
    const int qk = (lane >> 4) * 8, r16 = lane & 15;

    f32x4 acc[4][4];
#pragma unroll
    for (int i = 0; i < 4; i++)
#pragma unroll
        for (int j = 0; j < 4; j++) acc[i][j] = (f32x4){0.f, 0.f, 0.f, 0.f};

    for (int k0 = 0; k0 < 256; k0 += 32) {
#pragma unroll
        for (int i = 0; i < 2; i++) {
            int ch = t + i * 256;
            int m = ch >> 2;
            int ko = (ch & 3) * 8;
            int row = row0 + m;
            uint4 pk = (uint4){0u, 0u, 0u, 0u};
            if (row < M) pk = *(const uint4*)(A + (size_t)row * 256 + k0 + ko);
            *(uint4*)(&As[m][ko]) = pk;
            *(uint4*)(&Bs[m][ko]) = *(const uint4*)(Bt + (size_t)m * 256 + k0 + ko);
        }
        __syncthreads();
        short8 av[4], bv[4];
#pragma unroll
        for (int mt = 0; mt < 4; mt++) av[mt] = *(const short8*)(&As[wm + mt * 16 + r16][qk]);
#pragma unroll
        for (int nt = 0; nt < 4; nt++) bv[nt] = *(const short8*)(&Bs[wn + nt * 16 + r16][qk]);
#pragma unroll
        for (int mt = 0; mt < 4; mt++)
#pragma unroll
            for (int nt = 0; nt < 4; nt++)
                acc[mt][nt] = __builtin_amdgcn_mfma_f32_16x16x32_bf16(av[mt], bv[nt], acc[mt][nt], 0, 0, 0);
        __syncthreads();
    }
#pragma unroll
    for (int mt = 0; mt < 4; mt++) {
#pragma unroll
        for (int r = 0; r < 4; r++) {
            int row = row0 + wm + mt * 16 + (lane >> 4) * 4 + r;
            if (row >= M) continue;
#pragma unroll
            for (int nt = 0; nt < 4; nt++) {
                int col = wn + nt * 16 + r16;
                float v = acc[mt][nt][r];
                if (col < 64) {
                    out[(size_t)row * 64 + col] = v + bL1[col];
                } else {
                    out[(size_t)M * 64 + (size_t)row * 64 + (col - 64)] = v + bL2[col - 64];
                }
            }
        }
    }
}

// decode 16 fp8 (uint4) and FMA into a[16]
__device__ inline void acc16f8(float* a, uint4 r, float w) {
    f32x2 p;
    p = __builtin_amdgcn_cvt_pk_f32_fp8((int)r.x, false); a[0]  += w * p.x; a[1]  += w * p.y;
    p = __builtin_amdgcn_cvt_pk_f32_fp8((int)r.x, true);  a[2]  += w * p.x; a[3]  += w * p.y;
    p = __builtin_amdgcn_cvt_pk_f32_fp8((int)r.y, false); a[4]  += w * p.x; a[5]  += w * p.y;
    p = __builtin_amdgcn_cvt_pk_f32_fp8((int)r.y, true);  a[6]  += w * p.x; a[7]  += w * p.y;
    p = __builtin_amdgcn_cvt_pk_f32_fp8((int)r.z, false); a[8]  += w * p.x; a[9]  += w * p.y;
    p = __builtin_amdgcn_cvt_pk_f32_fp8((int)r.z, true);  a[10] += w * p.x; a[11] += w * p.y;
    p = __builtin_amdgcn_cvt_pk_f32_fp8((int)r.w, false); a[12] += w * p.x; a[13] += w * p.y;
    p = __builtin_amdgcn_cvt_pk_f32_fp8((int)r.w, true);  a[14] += w * p.x; a[15] += w * p.y;
}

// fp8-row SPMM: out[n][:] = relu(sum_e w_e * sup[src_e][:] + bias), rows 256B e4m3.
// One wave per node, FOUR 16-lane groups; group g handles edge e+g, lane holds
// 16 features (16B) -> one load instr covers 4 rows = 1KB. Combine via
// shfl_xor(16) + shfl_xor(32). Output bf16.
__global__ __launch_bounds__(256) void spmm_fp8_kernel(
    const unsigned char* __restrict__ sup, const int* __restrict__ rp,
    const int* __restrict__ esrc, const float* __restrict__ ew,
    const float* __restrict__ bias, unsigned short* __restrict__ out, int nnodes)
{
    const int wid = threadIdx.x >> 6, lane = threadIdx.x & 63;
    const int node = blockIdx.x * 4 + wid;
    if (node >= nnodes) return;
    const int g = lane >> 4;            // 0..3
    const int f16 = (lane & 15) * 16;   // feature index (and byte offset)
    const unsigned char* supf = sup + f16;
    const int beg = rp[node], end = rp[node + 1];

    float a[16];
#pragma unroll
    for (int i = 0; i < 16; i++) a[i] = 0.f;

    int e = beg;
    for (; e + 8 <= end; e += 8) {       // 2 chunks of 4 edges in flight
        const int s0 = esrc[e + g],     s1 = esrc[e + 4 + g];
        const float w0 = ew[e + g],     w1 = ew[e + 4 + g];
        const uint4 r0 = *(const uint4*)(supf + (size_t)s0 * 256);
        const uint4 r1 = *(const uint4*)(supf + (size_t)s1 * 256);
        acc16f8(a, r0, w0);
        acc16f8(a, r1, w1);
    }
    for (; e + 4 <= end; e += 4) {
        const int s = esrc[e + g];
        const float w = ew[e + g];
        const uint4 r = *(const uint4*)(supf + (size_t)s * 256);
        acc16f8(a, r, w);
    }
    {
        const int rem = end - e;         // 0..3
        if (g < rem) {
            const int s = esrc[e + g];
            const float w = ew[e + g];
            const uint4 r = *(const uint4*)(supf + (size_t)s * 256);
            acc16f8(a, r, w);
        }
    }
    // combine the 4 edge-groups (same features live in lanes L, L^16, L^32, L^48)
#pragma unroll
    for (int i = 0; i < 16; i++) {
        a[i] += __shfl_xor(a[i], 16);
        a[i] += __shfl_xor(a[i], 32);
    }

    if (g == 0) {
        const float4 b0 = *(const float4*)(bias + f16);
        const float4 b1 = *(const float4*)(bias + f16 + 4);
        const float4 b2 = *(const float4*)(bias + f16 + 8);
        const float4 b3 = *(const float4*)(bias + f16 + 12);
        a[0] += b0.x; a[1] += b0.y; a[2]  += b0.z; a[3]  += b0.w;
        a[4] += b1.x; a[5] += b1.y; a[6]  += b1.z; a[7]  += b1.w;
        a[8] += b2.x; a[9] += b2.y; a[10] += b2.z; a[11] += b2.w;
        a[12] += b3.x; a[13] += b3.y; a[14] += b3.z; a[15] += b3.w;
#pragma unroll
        for (int i = 0; i < 16; i++) a[i] = a[i] > 0.f ? a[i] : 0.f;
        uint4 o0, o1;
        o0.x = (unsigned int)f2bf(a[0])  | ((unsigned int)f2bf(a[1])  << 16);
        o0.y = (unsigned int)f2bf(a[2])  | ((unsigned int)f2bf(a[3])  << 16);
        o0.z = (unsigned int)f2bf(a[4])  | ((unsigned int)f2bf(a[5])  << 16);
        o0.w = (unsigned int)f2bf(a[6])  | ((unsigned int)f2bf(a[7])  << 16);
        o1.x = (unsigned int)f2bf(a[8])  | ((unsigned int)f2bf(a[9])  << 16);
        o1.y = (unsigned int)f2bf(a[10]) | ((unsigned int)f2bf(a[11]) << 16);
        o1.z = (unsigned int)f2bf(a[12]) | ((unsigned int)f2bf(a[13]) << 16);
        o1.w = (unsigned int)f2bf(a[14]) | ((unsigned int)f2bf(a[15]) << 16);
        *(uint4*)(out + (size_t)node * 256 + f16) = o0;
        *(uint4*)(out + (size_t)node * 256 + f16 + 8) = o1;
    }
}

extern "C" void kernel_launch(void* const* d_in, const int* in_sizes, int n_in,
                              void* d_out, int out_size, void* d_ws, size_t ws_size,
                              hipStream_t stream) {
    const float* x    = (const float*)d_in[0];
    const int*   esrc = (const int*)d_in[1];
    const int*   edst = (const int*)d_in[2];
    const float* ew   = (const float*)d_in[3];
    const float* W1   = (const float*)d_in[4];
    const float* b1   = (const float*)d_in[5];
    const float* W2   = (const float*)d_in[6];
    const float* b2   = (const float*)d_in[7];
    const float* WL1  = (const float*)d_in[8];
    const float* bL1  = (const float*)d_in[9];
    const float* WL2  = (const float*)d_in[10];
    const float* bL2  = (const float*)d_in[11];
    float* out = (float*)d_out;

    const int N = in_sizes[0] / 256;   // 100000
    const int E = in_sizes[1];         // 3200000

    char* ws = (char*)d_ws;
    size_t off = 0;
    auto alloc = [&](size_t bytes) -> void* {
        void* p = ws + off;
        off = (off + bytes + 511) & ~(size_t)511;   // 512B-align: rows stay line-aligned
        return p;
    };
    int* rp              = (int*)alloc((size_t)(N + 1) * 4);
    unsigned short* W1t  = (unsigned short*)alloc((size_t)256 * 256 * 2);
    unsigned short* W2t  = (unsigned short*)alloc((size_t)256 * 256 * 2);
    unsigned short* WLt  = (unsigned short*)alloc((size_t)128 * 256 * 2);
    unsigned char* sup8  = (unsigned char*)alloc((size_t)N * 256);      // fp8 support (both layers)
    unsigned short* hbuf = (unsigned short*)alloc((size_t)N * 256 * 2); // bf16 h (both layers)

    const int mblocks = (N + 127) / 128;

    rowptr_kernel<<<(E + 255) / 256, 256, 0, stream>>>(edst, rp, E, N);
    prep_kernel<<<640, 256, 0, stream>>>(W1, W2, WL1, WL2, W1t, W2t, WLt);

    // layer 1: support fp8 e4m3
    gemm_kernel<float, unsigned char><<<dim3(2, mblocks), 256, 0, stream>>>(
        x, W1t, sup8, N);
    spmm_fp8_kernel<<<(N + 3) / 4, 256, 0, stream>>>(
        sup8, rp, esrc, ew, b1, hbuf, N);
    // layer 2: support fp8 e4m3
    gemm_kernel<unsigned short, unsigned char><<<dim3(2, mblocks), 256, 0, stream>>>(
        hbuf, W2t, sup8, N);
    spmm_fp8_kernel<<<(N + 3) / 4, 256, 0, stream>>>(
        sup8, rp, esrc, ew, b2, hbuf, N);
    head_kernel<<<dim3(mblocks, 1), 256, 0, stream>>>(hbuf, WLt, bL1, bL2, out, N);
}

// Round 5
// 497.290 us; speedup vs baseline: 1.4769x; 1.0447x over previous
//
#include <hip/hip_runtime.h>
#include <hip/hip_bf16.h>

typedef __attribute__((ext_vector_type(8))) short short8;
typedef __attribute__((ext_vector_type(4))) float f32x4;
typedef __attribute__((ext_vector_type(2))) float f32x2;

__device__ inline unsigned short f2bf(float f) {
    union { float f; unsigned int u; } x; x.f = f;
    return (unsigned short)((x.u + 0x7fffu + ((x.u >> 16) & 1u)) >> 16);
}

// async global->LDS, 16B per lane. LDS dest must be wave-uniform base + lane*16.
#define ASYNC16(gptr, lptr)                                                      \
    __builtin_amdgcn_global_load_lds(                                            \
        (const __attribute__((address_space(1))) unsigned int*)(gptr),           \
        (__attribute__((address_space(3))) unsigned int*)(lptr), 16, 0, 0)

// feature permutation (per 64-block): stored position p holds original feature sg(p)
__device__ __host__ inline int sg(int j) {
    int p = j & 63;
    return (j & ~63) | ((p >> 2) + 16 * (p & 3));
}

// rp[n] = lower_bound(dst, n) via boundary diff (dst sorted). One streamed pass.
__global__ void rowptr_kernel(const int* __restrict__ dst, int* __restrict__ rp,
                              int E, int N) {
    int e = blockIdx.x * blockDim.x + threadIdx.x;
    if (e >= E) return;
    int d1 = dst[e];
    int d0 = (e == 0) ? -1 : dst[e - 1];
    for (int n = d0 + 1; n <= d1; n++) rp[n] = e;
    if (e <= N) {                      // tail: nodes past the last dst value
        int dlast = dst[E - 1];
        if (e > dlast) rp[e] = E;
    }
}

// x fp32 -> bf16 (round-half-up), 8 elements/thread
__global__ void x2bf_kernel(const float* __restrict__ x, unsigned short* __restrict__ xb,
                            int n8) {
    int i = blockIdx.x * blockDim.x + threadIdx.x;
    if (i >= n8) return;
    const uint4* p = (const uint4*)(x + (size_t)i * 8);
    uint4 u = p[0], v = p[1];
    uint4 pk;
    pk.x = ((u.x + 0x8000u) >> 16) | ((u.y + 0x8000u) & 0xffff0000u);
    pk.y = ((u.z + 0x8000u) >> 16) | ((u.w + 0x8000u) & 0xffff0000u);
    pk.z = ((v.x + 0x8000u) >> 16) | ((v.y + 0x8000u) & 0xffff0000u);
    pk.w = ((v.z + 0x8000u) >> 16) | ((v.w + 0x8000u) & 0xffff0000u);
    *(uint4*)(xb + (size_t)i * 8) = pk;
}

// Weight/bias prep. blocks 0..255 -> W1t (k not permuted), 256..511 -> W2t (k sg-permuted),
// 512..639 -> WLt (k sg-permuted), 640 -> b1p, 641 -> b2p (sg-permuted biases).
__global__ void prep_kernel(const float* __restrict__ W1, const float* __restrict__ W2,
                            const float* __restrict__ WL1, const float* __restrict__ WL2,
                            const float* __restrict__ b1, const float* __restrict__ b2,
                            unsigned short* __restrict__ W1t, unsigned short* __restrict__ W2t,
                            unsigned short* __restrict__ WLt,
                            float* __restrict__ b1p, float* __restrict__ b2p) {
    int b = blockIdx.x, k = threadIdx.x;
    if (b < 256) {
        W1t[(size_t)b * 256 + k] = f2bf(W1[(size_t)k * 256 + b]);
    } else if (b < 512) {
        int n = b - 256;
        W2t[(size_t)n * 256 + k] = f2bf(W2[(size_t)sg(k) * 256 + n]);
    } else if (b < 640) {
        int c = b - 512;
        int ks = sg(k);
        float v = (c < 64) ? WL1[(size_t)ks * 64 + c] : WL2[(size_t)ks * 64 + (c - 64)];
        WLt[(size_t)c * 256 + k] = f2bf(v);
    } else if (b == 640) {
        b1p[k] = b1[sg(k)];
    } else {
        b2p[k] = b2[sg(k)];
    }
}

// C8[M][256] fp8 = A[M][256](bf16) @ Bt^T, output columns sg-permuted per 64-block.
// m97-style: global_load_lds staging (16B/lane), unpadded LDS [128][32].
__global__ __launch_bounds__(256) void gemm_f8_kernel(
    const unsigned short* __restrict__ A, const unsigned short* __restrict__ Bt,
    unsigned char* __restrict__ C, int M)
{
    __shared__ __align__(16) unsigned short As[128 * 32];
    __shared__ __align__(16) unsigned short Bs[128 * 32];
    const int t = threadIdx.x;
    const int row0 = blockIdx.y * 128;
    const int col0 = blockIdx.x * 128;
    const int wid = t >> 6, lane = t & 63;
    const int wm = (wid >> 1) * 64, wn = (wid & 1) * 64;
    const int qk = (lane >> 4) * 8, r16 = lane & 15;

    // staging chunks: c covers (m = c>>2, ko = (c&3)*8); LDS offset = c*16B (lane-contiguous)
    const int c0 = t, c1 = t + 256;
    const int am0 = min(row0 + (c0 >> 2), M - 1);
    const int am1 = min(row0 + (c1 >> 2), M - 1);
    const int ak0 = (c0 & 3) * 8, ak1 = (c1 & 3) * 8;
    const int bm0 = col0 + (c0 >> 2), bm1 = col0 + (c1 >> 2);

    f32x4 acc[4][4];
#pragma unroll
    for (int i = 0; i < 4; i++)
#pragma unroll
        for (int j = 0; j < 4; j++) acc[i][j] = (f32x4){0.f, 0.f, 0.f, 0.f};

    for (int k0 = 0; k0 < 256; k0 += 32) {
        ASYNC16(A + (size_t)am0 * 256 + k0 + ak0, &As[c0 * 8]);
        ASYNC16(A + (size_t)am1 * 256 + k0 + ak1, &As[c1 * 8]);
        ASYNC16(Bt + (size_t)bm0 * 256 + k0 + ak0, &Bs[c0 * 8]);
        ASYNC16(Bt + (size_t)bm1 * 256 + k0 + ak1, &Bs[c1 * 8]);
        __syncthreads();
        short8 av[4], bv[4];
#pragma unroll
        for (int mt = 0; mt < 4; mt++) av[mt] = *(const short8*)(&As[(wm + mt * 16 + r16) * 32 + qk]);
#pragma unroll
        for (int nt = 0; nt < 4; nt++) bv[nt] = *(const short8*)(&Bs[(wn + nt * 16 + r16) * 32 + qk]);
#pragma unroll
        for (int mt = 0; mt < 4; mt++)
#pragma unroll
            for (int nt = 0; nt < 4; nt++)
                acc[mt][nt] = __builtin_amdgcn_mfma_f32_16x16x32_bf16(av[mt], bv[nt], acc[mt][nt], 0, 0, 0);
        __syncthreads();
    }
    // permuted fp8 epilogue: lane packs its 4 cols of one row into one dword.
    // stored[col0 + wn + r16*4 + nt] = fp8(orig col0 + wn + nt*16 + r16)  == sg-permutation
#pragma unroll
    for (int mt = 0; mt < 4; mt++) {
        const int rowb = row0 + wm + mt * 16 + (lane >> 4) * 4;
#pragma unroll
        for (int r = 0; r < 4; r++) {
            const int row = rowb + r;
            if (row >= M) continue;
            int w = 0;
            w = __builtin_amdgcn_cvt_pk_fp8_f32(acc[mt][0][r], acc[mt][1][r], w, false);
            w = __builtin_amdgcn_cvt_pk_fp8_f32(acc[mt][2][r], acc[mt][3][r], w, true);
            *(unsigned int*)(C + (size_t)row * 256 + col0 + wn + r16 * 4) = (unsigned int)w;
        }
    }
}

// logits = h2 @ WLt^T + bias (WLt k-dim pre-permuted to match h2's sg order).
// cols 0..63 -> out0, 64..127 -> out1 (concatenated). Same m97 staging.
__global__ __launch_bounds__(256) void head_kernel(
    const unsigned short* __restrict__ A, const unsigned short* __restrict__ Bt,
    const float* __restrict__ bL1, const float* __restrict__ bL2,
    float* __restrict__ out, int M)
{
    __shared__ __align__(16) unsigned short As[128 * 32];
    __shared__ __align__(16) unsigned short Bs[128 * 32];
    const int t = threadIdx.x;
    const int row0 = blockIdx.x * 128;
    const int wid = t >> 6, lane = t & 63;
    const int wm = (wid >> 1) * 64, wn = (wid & 1) * 64;
    const int qk = (lane >> 4) * 8, r16 = lane & 15;

    const int c0 = t, c1 = t + 256;
    const int am0 = min(row0 + (c0 >> 2), M - 1);
    const int am1 = min(row0 + (c1 >> 2), M - 1);
    const int ak0 = (c0 & 3) * 8, ak1 = (c1 & 3) * 8;
    const int bm0 = c0 >> 2, bm1 = c1 >> 2;          // B has exactly 128 rows

    f32x4 acc[4][4];
#pragma unroll
    for (int i = 0; i < 4; i++)
#pragma unroll
        for (int j = 0; j < 4; j++) acc[i][j] = (f32x4){0.f, 0.f, 0.f, 0.f};

    for (int k0 = 0; k0 < 256; k0 += 32) {
        ASYNC16(A + (size_t)am0 * 256 + k0 + ak0, &As[c0 * 8]);
        ASYNC16(A + (size_t)am1 * 256 + k0 + ak1, &As[c1 * 8]);
        ASYNC16(Bt + (size_t)bm0 * 256 + k0 + ak0, &Bs[c0 * 8]);
        ASYNC16(Bt + (size_t)bm1 * 256 + k0 + ak1, &Bs[c1 * 8]);
        __syncthreads();
        short8 av[4], bv[4];
#pragma unroll
        for (int mt = 0; mt < 4; mt++) av[mt] = *(const short8*)(&As[(wm + mt * 16 + r16) * 32 + qk]);
#pragma unroll
        for (int nt = 0; nt < 4; nt++) bv[nt] = *(const short8*)(&Bs[(wn + nt * 16 + r16) * 32 + qk]);
#pragma unroll
        for (int mt = 0; mt < 4; mt++)
#pragma unroll
            for (int nt = 0; nt < 4; nt++)
                acc[mt][nt] = __builtin_amdgcn_mfma_f32_16x16x32_bf16(av[mt], bv[nt], acc[mt][nt], 0, 0, 0);
        __syncthreads();
    }
#pragma unroll
    for (int mt = 0; mt < 4; mt++) {
#pragma unroll
        for (int r = 0; r < 4; r++) {
            int row = row0 + wm + mt * 16 + (lane >> 4) * 4 + r;
            if (row >= M) continue;
#pragma unroll
            for (int nt = 0; nt < 4; nt++) {
                int col = wn + nt * 16 + r16;
                float v = acc[mt][nt][r];
                if (col < 64) {
                    out[(size_t)row * 64 + col] = v + bL1[col];
                } else {
                    out[(size_t)M * 64 + (size_t)row * 64 + (col - 64)] = v + bL2[col - 64];
                }
            }
        }
    }
}

// decode 16 fp8 (uint4) and FMA into a[16]
__device__ inline void acc16f8(float* a, uint4 r, float w) {
    f32x2 p;
    p = __builtin_amdgcn_cvt_pk_f32_fp8((int)r.x, false); a[0]  += w * p.x; a[1]  += w * p.y;
    p = __builtin_amdgcn_cvt_pk_f32_fp8((int)r.x, true);  a[2]  += w * p.x; a[3]  += w * p.y;
    p = __builtin_amdgcn_cvt_pk_f32_fp8((int)r.y, false); a[4]  += w * p.x; a[5]  += w * p.y;
    p = __builtin_amdgcn_cvt_pk_f32_fp8((int)r.y, true);  a[6]  += w * p.x; a[7]  += w * p.y;
    p = __builtin_amdgcn_cvt_pk_f32_fp8((int)r.z, false); a[8]  += w * p.x; a[9]  += w * p.y;
    p = __builtin_amdgcn_cvt_pk_f32_fp8((int)r.z, true);  a[10] += w * p.x; a[11] += w * p.y;
    p = __builtin_amdgcn_cvt_pk_f32_fp8((int)r.w, false); a[12] += w * p.x; a[13] += w * p.y;
    p = __builtin_amdgcn_cvt_pk_f32_fp8((int)r.w, true);  a[14] += w * p.x; a[15] += w * p.y;
}

// fp8-row SPMM: out[n][:] = relu(sum_e w_e * sup[src_e][:] + bias), rows 256B e4m3.
// One wave per node, FOUR 16-lane groups; group g handles edge e+g, lane holds
// 16 features (16B) -> one load instr covers 4 rows = 1KB. Combine via
// shfl_xor(16) + shfl_xor(32). Output bf16. (Features sg-permuted transparently.)
__global__ __launch_bounds__(256) void spmm_fp8_kernel(
    const unsigned char* __restrict__ sup, const int* __restrict__ rp,
    const int* __restrict__ esrc, const float* __restrict__ ew,
    const float* __restrict__ bias, unsigned short* __restrict__ out, int nnodes)
{
    const int wid = threadIdx.x >> 6, lane = threadIdx.x & 63;
    const int node = blockIdx.x * 4 + wid;
    if (node >= nnodes) return;
    const int g = lane >> 4;            // 0..3
    const int f16 = (lane & 15) * 16;   // feature index (and byte offset)
    const unsigned char* supf = sup + f16;
    const int beg = rp[node], end = rp[node + 1];

    float a[16];
#pragma unroll
    for (int i = 0; i < 16; i++) a[i] = 0.f;

    int e = beg;
    for (; e + 8 <= end; e += 8) {       // 2 chunks of 4 edges in flight
        const int s0 = esrc[e + g],     s1 = esrc[e + 4 + g];
        const float w0 = ew[e + g],     w1 = ew[e + 4 + g];
        const uint4 r0 = *(const uint4*)(supf + (size_t)s0 * 256);
        const uint4 r1 = *(const uint4*)(supf + (size_t)s1 * 256);
        acc16f8(a, r0, w0);
        acc16f8(a, r1, w1);
    }
    for (; e + 4 <= end; e += 4) {
        const int s = esrc[e + g];
        const float w = ew[e + g];
        const uint4 r = *(const uint4*)(supf + (size_t)s * 256);
        acc16f8(a, r, w);
    }
    {
        const int rem = end - e;         // 0..3
        if (g < rem) {
            const int s = esrc[e + g];
            const float w = ew[e + g];
            const uint4 r = *(const uint4*)(supf + (size_t)s * 256);
            acc16f8(a, r, w);
        }
    }
#pragma unroll
    for (int i = 0; i < 16; i++) {
        a[i] += __shfl_xor(a[i], 16);
        a[i] += __shfl_xor(a[i], 32);
    }

    if (g == 0) {
        const float4 b0 = *(const float4*)(bias + f16);
        const float4 b1 = *(const float4*)(bias + f16 + 4);
        const float4 b2 = *(const float4*)(bias + f16 + 8);
        const float4 b3 = *(const float4*)(bias + f16 + 12);
        a[0] += b0.x; a[1] += b0.y; a[2]  += b0.z; a[3]  += b0.w;
        a[4] += b1.x; a[5] += b1.y; a[6]  += b1.z; a[7]  += b1.w;
        a[8] += b2.x; a[9] += b2.y; a[10] += b2.z; a[11] += b2.w;
        a[12] += b3.x; a[13] += b3.y; a[14] += b3.z; a[15] += b3.w;
#pragma unroll
        for (int i = 0; i < 16; i++) a[i] = a[i] > 0.f ? a[i] : 0.f;
        uint4 o0, o1;
        o0.x = (unsigned int)f2bf(a[0])  | ((unsigned int)f2bf(a[1])  << 16);
        o0.y = (unsigned int)f2bf(a[2])  | ((unsigned int)f2bf(a[3])  << 16);
        o0.z = (unsigned int)f2bf(a[4])  | ((unsigned int)f2bf(a[5])  << 16);
        o0.w = (unsigned int)f2bf(a[6])  | ((unsigned int)f2bf(a[7])  << 16);
        o1.x = (unsigned int)f2bf(a[8])  | ((unsigned int)f2bf(a[9])  << 16);
        o1.y = (unsigned int)f2bf(a[10]) | ((unsigned int)f2bf(a[11]) << 16);
        o1.z = (unsigned int)f2bf(a[12]) | ((unsigned int)f2bf(a[13]) << 16);
        o1.w = (unsigned int)f2bf(a[14]) | ((unsigned int)f2bf(a[15]) << 16);
        *(uint4*)(out + (size_t)node * 256 + f16) = o0;
        *(uint4*)(out + (size_t)node * 256 + f16 + 8) = o1;
    }
}

extern "C" void kernel_launch(void* const* d_in, const int* in_sizes, int n_in,
                              void* d_out, int out_size, void* d_ws, size_t ws_size,
                              hipStream_t stream) {
    const float* x    = (const float*)d_in[0];
    const int*   esrc = (const int*)d_in[1];
    const int*   edst = (const int*)d_in[2];
    const float* ew   = (const float*)d_in[3];
    const float* W1   = (const float*)d_in[4];
    const float* b1   = (const float*)d_in[5];
    const float* W2   = (const float*)d_in[6];
    const float* b2   = (const float*)d_in[7];
    const float* WL1  = (const float*)d_in[8];
    const float* bL1  = (const float*)d_in[9];
    const float* WL2  = (const float*)d_in[10];
    const float* bL2  = (const float*)d_in[11];
    float* out = (float*)d_out;

    const int N = in_sizes[0] / 256;   // 100000
    const int E = in_sizes[1];         // 3200000

    char* ws = (char*)d_ws;
    size_t off = 0;
    auto alloc = [&](size_t bytes) -> void* {
        void* p = ws + off;
        off = (off + bytes + 511) & ~(size_t)511;   // 512B-align: rows stay line-aligned
        return p;
    };
    int* rp              = (int*)alloc((size_t)(N + 1) * 4);
    unsigned short* W1t  = (unsigned short*)alloc((size_t)256 * 256 * 2);
    unsigned short* W2t  = (unsigned short*)alloc((size_t)256 * 256 * 2);
    unsigned short* WLt  = (unsigned short*)alloc((size_t)128 * 256 * 2);
    float* b1p           = (float*)alloc(256 * 4);
    float* b2p           = (float*)alloc(256 * 4);
    unsigned char* sup8  = (unsigned char*)alloc((size_t)N * 256);      // fp8 support (both layers)
    unsigned short* hbuf = (unsigned short*)alloc((size_t)N * 256 * 2); // xb, then h1/h2 (aliased:
                                                                        // xb dead once gemm1 done)

    const int mblocks = (N + 127) / 128;

    rowptr_kernel<<<(E + 255) / 256, 256, 0, stream>>>(edst, rp, E, N);
    x2bf_kernel<<<(N * 256 / 8 + 255) / 256, 256, 0, stream>>>(x, hbuf, N * 256 / 8);
    prep_kernel<<<642, 256, 0, stream>>>(W1, W2, WL1, WL2, b1, b2, W1t, W2t, WLt, b1p, b2p);

    // layer 1: support fp8 e4m3 (sg-permuted cols)
    gemm_f8_kernel<<<dim3(2, mblocks), 256, 0, stream>>>(hbuf, W1t, sup8, N);
    spmm_fp8_kernel<<<(N + 3) / 4, 256, 0, stream>>>(sup8, rp, esrc, ew, b1p, hbuf, N);
    // layer 2 (W2t k-rows pre-permuted to consume sg order; output sg-permuted again)
    gemm_f8_kernel<<<dim3(2, mblocks), 256, 0, stream>>>(hbuf, W2t, sup8, N);
    spmm_fp8_kernel<<<(N + 3) / 4, 256, 0, stream>>>(sup8, rp, esrc, ew, b2p, hbuf, N);
    head_kernel<<<mblocks, 256, 0, stream>>>(hbuf, WLt, bL1, bL2, out, N);
}